// Round 1
// baseline (4221.714 us; speedup 1.0000x reference)
//
#include <hip/hip_runtime.h>

namespace {
constexpr int Bn = 4;
constexpr int Cc = 256;    // C
constexpr int Nn = 8192;   // N
constexpr int Kk = 16;     // K
constexpr int CSh = 128;   // per-scale channels
constexpr int TP = 16;     // points per block
constexpr float EPSf = 1e-5f;
constexpr float SCALEf = 0.17677669529663687f; // 32^-0.5

// LDS float offsets (single pool, reused across stages)
constexpr int OFF_U  = 0;                   // x_sh [256][20]  OR  y_sh [128][20]
constexpr int OFF_Z  = 2560;                // z_sh [128][20] (overlaps x_sh upper half)
constexpr int OFF_Q  = 5120;                // q_sh [16][256]
constexpr int OFF_A  = OFF_Q + TP * Cc;     // 9216: attT [256][20]
constexpr int OFF_KV = OFF_A + Cc * 20;     // 14336: kv [256][16]
constexpr int OFF_LG = OFF_KV + 256 * 16;   // 18432: logits [4][16]
constexpr int SMEM_F = OFF_LG + 64;         // 18496 floats = 73984 B
}

__global__ __launch_bounds__(256, 2) void plsa_fused(
    const float* __restrict__ x,
    const float* __restrict__ y0,
    const float* __restrict__ y1,
    const float* __restrict__ q_w,
    const float* __restrict__ conv0_w,
    const float* __restrict__ bn0_g, const float* __restrict__ bn0_b,
    const float* __restrict__ bn0_m, const float* __restrict__ bn0_v,
    const float* __restrict__ kv0_w,
    const float* __restrict__ conv1_w,
    const float* __restrict__ bn1_g, const float* __restrict__ bn1_b,
    const float* __restrict__ bn1_m, const float* __restrict__ bn1_v,
    const float* __restrict__ kv1_w,
    const float* __restrict__ proj_w, const float* __restrict__ proj_b,
    float* __restrict__ out)
{
    __shared__ __align__(16) float sm[SMEM_F];
    const int tid = threadIdx.x;
    const int bid = blockIdx.x;
    const int b  = bid / (Nn / TP);
    const int n0 = (bid % (Nn / TP)) * TP;

    // ---------------- stage 1: load x tile [256 ch][16 pts] ----------------
    {
        const float* xp = x + ((size_t)b * Cc + tid) * Nn + n0;
        const float4* xp4 = reinterpret_cast<const float4*>(xp);
        float4* xr = reinterpret_cast<float4*>(&sm[OFF_U + tid * 20]);
        xr[0] = xp4[0]; xr[1] = xp4[1]; xr[2] = xp4[2]; xr[3] = xp4[3];
    }
    __syncthreads();

    // ---------------- stage 2: q = q_w @ x  -> q_sh[p][o] ----------------
    {
        float acc[TP];
        #pragma unroll
        for (int p = 0; p < TP; ++p) acc[p] = 0.f;
        const float* wrow = q_w + (size_t)tid * Cc;
        for (int c = 0; c < Cc; ++c) {
            const float w = wrow[c];
            const float* xr = &sm[OFF_U + c * 20];
            #pragma unroll
            for (int p = 0; p < TP; ++p) acc[p] += w * xr[p];
        }
        #pragma unroll
        for (int p = 0; p < TP; ++p) sm[OFF_Q + p * Cc + tid] = acc[p];
    }
    __syncthreads();

    // ---------------- stage 3: two scale branches ----------------
    for (int br = 0; br < 2; ++br) {
        const int cin = br ? 128 : 64;
        const float* yb = br ? y1 : y0;
        const float* cw = br ? conv1_w : conv0_w;
        const float* bg = br ? bn1_g : bn0_g;
        const float* bb = br ? bn1_b : bn0_b;
        const float* bm = br ? bn1_m : bn0_m;
        const float* bv = br ? bn1_v : bn0_v;
        const float* kw = br ? kv1_w : kv0_w;
        const int qb = br * 128;   // q-channel base and output-channel base

        // per-thread BN constants for the conv stage (thread -> (o, k-half))
        const int o_c = tid & 127;
        const int kh  = tid >> 7;
        const float inv = bg[o_c] * rsqrtf(bv[o_c] + EPSf);
        const float mo  = bm[o_c];
        const float bo  = bb[o_c];

        for (int p = 0; p < TP; ++p) {
            // ---- load y[:, n0+p, :] : cin x 16 ----
            {
                const int nf4 = cin * 4;  // float4 count
                for (int idx = tid; idx < nf4; idx += 256) {
                    const int cch = idx >> 2, kq = idx & 3;
                    const float4 v = reinterpret_cast<const float4*>(
                        yb + (((size_t)b * cin + cch) * Nn + (n0 + p)) * Kk)[kq];
                    reinterpret_cast<float4*>(&sm[OFF_U + cch * 20 + kq * 4])[0] = v;
                }
            }
            __syncthreads();

            // ---- conv (1x1) + BN + ReLU -> z_sh[o][k] ----
            {
                float a8[8];
                #pragma unroll
                for (int j = 0; j < 8; ++j) a8[j] = 0.f;
                const float* wrow = cw + o_c * cin;
                for (int cch = 0; cch < cin; ++cch) {
                    const float w = wrow[cch];
                    const float* yr = &sm[OFF_U + cch * 20 + kh * 8];
                    #pragma unroll
                    for (int j = 0; j < 8; ++j) a8[j] += w * yr[j];
                }
                float* zr = &sm[OFF_Z + o_c * 20 + kh * 8];
                #pragma unroll
                for (int j = 0; j < 8; ++j) {
                    const float zz = (a8[j] - mo) * inv + bo;
                    zr[j] = fmaxf(zz, 0.f);
                }
            }
            __syncthreads();

            // ---- kv = kv_w @ z : thread j computes kv[j][0..15] ----
            {
                float a16[16];
                #pragma unroll
                for (int k = 0; k < 16; ++k) a16[k] = 0.f;
                const float* wrow = kw + (size_t)tid * CSh;
                for (int o = 0; o < CSh; ++o) {
                    const float w = wrow[o];
                    const float* zr = &sm[OFF_Z + o * 20];
                    #pragma unroll
                    for (int k = 0; k < 16; ++k) a16[k] += w * zr[k];
                }
                float* kvr = &sm[OFF_KV + tid * 16];
                #pragma unroll
                for (int k = 0; k < 16; ++k) kvr[k] = a16[k];
            }
            __syncthreads();

            // ---- attention logits: thread (h, kk), h<4 ----
            if (tid < 64) {
                const int h = tid >> 4, kk = tid & 15;
                const float* qr = &sm[OFF_Q + p * Cc + qb + h * 32];
                float s = 0.f;
                #pragma unroll
                for (int d = 0; d < 32; ++d)
                    s += qr[d] * sm[OFF_KV + (h * 64 + 2 * d) * 16 + kk];
                sm[OFF_LG + h * 16 + kk] = s * SCALEf;
            }
            __syncthreads();

            // ---- softmax over 16 keys (4 threads) ----
            if (tid < 4) {
                float* lg = &sm[OFF_LG + tid * 16];
                float mx = lg[0];
                #pragma unroll
                for (int kk = 1; kk < 16; ++kk) mx = fmaxf(mx, lg[kk]);
                float e[16]; float sum = 0.f;
                #pragma unroll
                for (int kk = 0; kk < 16; ++kk) { e[kk] = __expf(lg[kk] - mx); sum += e[kk]; }
                const float r = 1.f / sum;
                #pragma unroll
                for (int kk = 0; kk < 16; ++kk) lg[kk] = e[kk] * r;
            }
            __syncthreads();

            // ---- out = attn @ v : thread (h, d), 128 threads ----
            if (tid < 128) {
                const int h = tid >> 5, d = tid & 31;
                float s = 0.f;
                #pragma unroll
                for (int kk = 0; kk < 16; ++kk)
                    s += sm[OFF_LG + h * 16 + kk] *
                         sm[OFF_KV + (h * 64 + 2 * d + 1) * 16 + kk];
                sm[OFF_A + (qb + h * 32 + d) * 20 + p] = s;
            }
            __syncthreads();
        }
    }

    // ---------------- stage 4: proj + bias, write out[b, co, n0..] ----------------
    {
        float acc[TP];
        #pragma unroll
        for (int p = 0; p < TP; ++p) acc[p] = 0.f;
        const float* wrow = proj_w + (size_t)tid * Cc;
        for (int ci = 0; ci < Cc; ++ci) {
            const float w = wrow[ci];
            const float* ar = &sm[OFF_A + ci * 20];
            #pragma unroll
            for (int p = 0; p < TP; ++p) acc[p] += w * ar[p];
        }
        const float pb = proj_b[tid];
        float* op = out + ((size_t)b * Cc + tid) * Nn + n0;
        #pragma unroll
        for (int p = 0; p < TP; ++p) op[p] = acc[p] + pb;
    }
}

extern "C" void kernel_launch(void* const* d_in, const int* in_sizes, int n_in,
                              void* d_out, int out_size, void* d_ws, size_t ws_size,
                              hipStream_t stream) {
    const float* x       = (const float*)d_in[0];
    const float* y0      = (const float*)d_in[1];
    const float* y1      = (const float*)d_in[2];
    const float* q_w     = (const float*)d_in[3];
    const float* conv0_w = (const float*)d_in[4];
    const float* bn0_g   = (const float*)d_in[5];
    const float* bn0_b   = (const float*)d_in[6];
    const float* bn0_m   = (const float*)d_in[7];
    const float* bn0_v   = (const float*)d_in[8];
    const float* kv0_w   = (const float*)d_in[9];
    const float* conv1_w = (const float*)d_in[10];
    const float* bn1_g   = (const float*)d_in[11];
    const float* bn1_b   = (const float*)d_in[12];
    const float* bn1_m   = (const float*)d_in[13];
    const float* bn1_v   = (const float*)d_in[14];
    const float* kv1_w   = (const float*)d_in[15];
    const float* proj_w  = (const float*)d_in[16];
    const float* proj_b  = (const float*)d_in[17];
    float* outp = (float*)d_out;

    dim3 grid(Bn * (Nn / TP));
    plsa_fused<<<grid, 256, 0, stream>>>(
        x, y0, y1, q_w, conv0_w, bn0_g, bn0_b, bn0_m, bn0_v, kv0_w,
        conv1_w, bn1_g, bn1_b, bn1_m, bn1_v, kv1_w, proj_w, proj_b, outp);
}

// Round 2
// 2128.212 us; speedup vs baseline: 1.9837x; 1.9837x over previous
//
#include <hip/hip_runtime.h>

typedef __attribute__((ext_vector_type(8))) short bf16x8;
typedef __attribute__((ext_vector_type(4))) float f32x4;
typedef unsigned short ushort_t;
typedef unsigned int uint_t;

#define MFMA(a, b, c) __builtin_amdgcn_mfma_f32_16x16x32_bf16(a, b, c, 0, 0, 0)

namespace {
constexpr int Bn = 4;
constexpr int Cc = 256;
constexpr int Nn = 8192;
constexpr float SCALEf = 0.17677669529663687f; // 32^-0.5
constexpr float EPSf = 1e-5f;

// d_ws byte offsets (bf16 weights + folded BN bias)
constexpr size_t WS_QW  = 0;        // 256*256*2 = 131072
constexpr size_t WS_PW  = 131072;   // 131072
constexpr size_t WS_KW0 = 262144;   // 256*128*2 = 65536
constexpr size_t WS_KW1 = 327680;   // 65536
constexpr size_t WS_CW0 = 393216;   // 128*64*2 = 16384
constexpr size_t WS_CW1 = 409600;   // 128*128*2 = 32768
constexpr size_t WS_CB0 = 442368;   // 128*4 = 512 (f32)
constexpr size_t WS_CB1 = 442880;   // 512
}

__device__ __forceinline__ uint_t f2b(float f) {
    union { float f; uint_t u; } v; v.f = f;
    return (v.u + 0x7fffu + ((v.u >> 16) & 1u)) >> 16;   // RNE
}
__device__ __forceinline__ float b2f(ushort_t u) {
    union { uint_t u; float f; } v; v.u = ((uint_t)u) << 16;
    return v.f;
}

// swizzled element offset in a bf16 LDS tile [R][KC]; 16B-chunk XOR on row
template<int KC>
__device__ __forceinline__ int swz(int r, int c) {
    constexpr int SW = (KC / 8 < 16 ? KC / 8 : 16);
    return r * KC + ((((c >> 3) ^ (r & (SW - 1))) << 3) | (c & 7));
}

// -------- prep: f32 weights -> bf16 (+ BN fold into conv weights) --------
__global__ void plsa_prep(const float* __restrict__ qw,
                          const float* __restrict__ c0w, const float* __restrict__ g0,
                          const float* __restrict__ b0,  const float* __restrict__ m0,
                          const float* __restrict__ v0,  const float* __restrict__ k0w,
                          const float* __restrict__ c1w, const float* __restrict__ g1,
                          const float* __restrict__ b1,  const float* __restrict__ m1,
                          const float* __restrict__ v1,  const float* __restrict__ k1w,
                          const float* __restrict__ pw,  char* ws) {
    const int i = blockIdx.x * 256 + threadIdx.x;   // 0 .. 65535
    ushort_t* qwb  = (ushort_t*)(ws + WS_QW);
    ushort_t* pwb  = (ushort_t*)(ws + WS_PW);
    ushort_t* kw0b = (ushort_t*)(ws + WS_KW0);
    ushort_t* kw1b = (ushort_t*)(ws + WS_KW1);
    ushort_t* cw0b = (ushort_t*)(ws + WS_CW0);
    ushort_t* cw1b = (ushort_t*)(ws + WS_CW1);
    float* cb0 = (float*)(ws + WS_CB0);
    float* cb1 = (float*)(ws + WS_CB1);

    qwb[i] = (ushort_t)f2b(qw[i]);
    pwb[i] = (ushort_t)f2b(pw[i]);
    if (i < 32768) { kw0b[i] = (ushort_t)f2b(k0w[i]); kw1b[i] = (ushort_t)f2b(k1w[i]); }
    if (i < 8192)  { int o = i >> 6;  float inv = g0[o] * rsqrtf(v0[o] + EPSf);
                     cw0b[i] = (ushort_t)f2b(c0w[i] * inv); }
    if (i < 16384) { int o = i >> 7;  float inv = g1[o] * rsqrtf(v1[o] + EPSf);
                     cw1b[i] = (ushort_t)f2b(c1w[i] * inv); }
    if (i < 128) {
        float i0 = g0[i] * rsqrtf(v0[i] + EPSf);
        float i1 = g1[i] * rsqrtf(v1[i] + EPSf);
        cb0[i] = b0[i] - m0[i] * i0;
        cb1[i] = b1[i] - m1[i] * i1;
    }
}

// -------- per-branch, per-chunk (4 points = 64 gemm cols) pipeline --------
template<int CIN>
__device__ __forceinline__ void scale_branch_chunk(
    int tid, int b, int n0, int n4, int qb,
    const float* __restrict__ yb,
    const ushort_t* __restrict__ cwb, const float* __restrict__ cbb,
    const ushort_t* __restrict__ kwb,
    ushort_t* Ytc, ushort_t* Ztc, ushort_t* Kc, ushort_t* Vc, float* psh,
    const ushort_t* Qs, ushort_t* Atl) {

    const int w = tid >> 6, lane = tid & 63, l15 = lane & 15, lk = lane >> 4;

    // ---- stage Y: f32 global -> bf16 LDS  Ytc[pk(64)][CIN] (c-pair packed) ----
    {
        constexpr int ITER = CIN * 64 / 512;
        #pragma unroll
        for (int it = 0; it < ITER; ++it) {
            const int idx = tid + it * 256;
            const int pk = idx & 63, c0 = (idx >> 6) * 2;
            const float* ys = yb + ((size_t)(b * CIN + c0)) * (Nn * 16)
                                 + (size_t)(n0 + n4 + (pk >> 4)) * 16 + (pk & 15);
            const float f0 = ys[0];
            const float f1 = ys[Nn * 16];
            *(uint_t*)(Ytc + swz<CIN>(pk, c0)) = f2b(f0) | (f2b(f1) << 16);
        }
    }
    __syncthreads();

    // ---- conv GEMM: Z[128 o][64 col] = CW'[o][c] * Y[c][col], +bias, relu ----
    {
        f32x4 acc[8];
        #pragma unroll
        for (int m = 0; m < 8; ++m) acc[m] = f32x4{0.f, 0.f, 0.f, 0.f};
        #pragma unroll
        for (int k = 0; k < CIN / 32; ++k) {
            bf16x8 bf = *(const bf16x8*)(Ytc + swz<CIN>(w * 16 + l15, k * 32 + lk * 8));
            #pragma unroll
            for (int m = 0; m < 8; ++m) {
                bf16x8 af = *(const bf16x8*)(cwb + (m * 16 + l15) * CIN + k * 32 + lk * 8);
                acc[m] = MFMA(af, bf, acc[m]);
            }
        }
        const int col = w * 16 + l15;
        #pragma unroll
        for (int m = 0; m < 8; ++m) {
            const int o0 = m * 16 + lk * 4;
            const float4 cb4 = *(const float4*)(cbb + o0);
            const float z0 = fmaxf(acc[m].x + cb4.x, 0.f);
            const float z1 = fmaxf(acc[m].y + cb4.y, 0.f);
            const float z2 = fmaxf(acc[m].z + cb4.z, 0.f);
            const float z3 = fmaxf(acc[m].w + cb4.w, 0.f);
            const int off = swz<128>(col, o0);
            *(uint_t*)(Ztc + off)     = f2b(z0) | (f2b(z1) << 16);
            *(uint_t*)(Ztc + off + 2) = f2b(z2) | (f2b(z3) << 16);
        }
    }
    __syncthreads();

    // ---- kv GEMM: KV[256 j][64 col] = KW[j][o] * Z[o][col]; split K/V ----
    {
        bf16x8 bfr[4];
        #pragma unroll
        for (int k = 0; k < 4; ++k)
            bfr[k] = *(const bf16x8*)(Ztc + swz<128>(w * 16 + l15, k * 32 + lk * 8));
        const int col = w * 16 + l15;
        #pragma unroll
        for (int mh = 0; mh < 2; ++mh) {
            f32x4 acc[8];
            #pragma unroll
            for (int mm = 0; mm < 8; ++mm) acc[mm] = f32x4{0.f, 0.f, 0.f, 0.f};
            #pragma unroll
            for (int k = 0; k < 4; ++k) {
                #pragma unroll
                for (int mm = 0; mm < 8; ++mm) {
                    const int m = mh * 8 + mm;
                    bf16x8 af = *(const bf16x8*)(kwb + (m * 16 + l15) * 128 + k * 32 + lk * 8);
                    acc[mm] = MFMA(af, bfr[k], acc[mm]);
                }
            }
            #pragma unroll
            for (int mm = 0; mm < 8; ++mm) {
                const int j0 = (mh * 8 + mm) * 16 + lk * 4;   // rows j0..j0+3
                const int h = j0 >> 6;
                const int d0 = (j0 & 63) >> 1;                // even
                // rows: K(d0), V(d0), K(d0+1), V(d0+1)
                *(uint_t*)(Kc + swz<128>(col, h * 32 + d0)) = f2b(acc[mm].x) | (f2b(acc[mm].z) << 16);
                Vc[swz<64>(h * 32 + d0,     col)] = (ushort_t)f2b(acc[mm].y);
                Vc[swz<64>(h * 32 + d0 + 1, col)] = (ushort_t)f2b(acc[mm].w);
            }
        }
    }
    __syncthreads();

    // ---- logits + softmax: thread = (n=wave, h=lk, kk=l15) ----
    {
        const int n = tid >> 6, h = lk, kk = l15;
        float s = 0.f;
        #pragma unroll
        for (int dc = 0; dc < 4; ++dc) {
            bf16x8 q8 = *(const bf16x8*)(Qs + swz<256>(n4 + n, qb + h * 32 + dc * 8));
            bf16x8 k8 = *(const bf16x8*)(Kc + swz<128>(n * 16 + kk, h * 32 + dc * 8));
            #pragma unroll
            for (int j = 0; j < 8; ++j)
                s += b2f((ushort_t)q8[j]) * b2f((ushort_t)k8[j]);
        }
        s *= SCALEf;
        float mx = s;
        #pragma unroll
        for (int msk = 1; msk < 16; msk <<= 1) mx = fmaxf(mx, __shfl_xor(mx, msk));
        const float e = __expf(s - mx);
        float sum = e;
        #pragma unroll
        for (int msk = 1; msk < 16; msk <<= 1) sum += __shfl_xor(sum, msk);
        psh[(n * 4 + h) * 20 + kk] = e / sum;
    }
    __syncthreads();

    // ---- PV: thread = (n, h, dd), d = dd and dd+16 ----
    {
        const int n = tid >> 6, h = lk, dd = l15;
        float pv[16];
        #pragma unroll
        for (int kk = 0; kk < 16; ++kk) pv[kk] = psh[(n * 4 + h) * 20 + kk];
        float o_lo = 0.f, o_hi = 0.f;
        bf16x8 va = *(const bf16x8*)(Vc + swz<64>(h * 32 + dd, n * 16));
        bf16x8 vb = *(const bf16x8*)(Vc + swz<64>(h * 32 + dd, n * 16 + 8));
        bf16x8 vc = *(const bf16x8*)(Vc + swz<64>(h * 32 + dd + 16, n * 16));
        bf16x8 vd = *(const bf16x8*)(Vc + swz<64>(h * 32 + dd + 16, n * 16 + 8));
        #pragma unroll
        for (int j = 0; j < 8; ++j) {
            o_lo += pv[j] * b2f((ushort_t)va[j]);
            o_lo += pv[8 + j] * b2f((ushort_t)vb[j]);
            o_hi += pv[j] * b2f((ushort_t)vc[j]);
            o_hi += pv[8 + j] * b2f((ushort_t)vd[j]);
        }
        Atl[swz<256>(n4 + n, qb + h * 32 + dd)]      = (ushort_t)f2b(o_lo);
        Atl[swz<256>(n4 + n, qb + h * 32 + dd + 16)] = (ushort_t)f2b(o_hi);
    }
    __syncthreads();
}

// ------------------------------- main kernel -------------------------------
__global__ __launch_bounds__(256, 2) void plsa_mfma(
    const float* __restrict__ x, const float* __restrict__ y0, const float* __restrict__ y1,
    const char* __restrict__ ws, const float* __restrict__ proj_b,
    float* __restrict__ out) {

    __shared__ __align__(16) ushort_t pool[40960];   // 80 KB
    ushort_t* Qs  = pool;            // [16][256] bf16 (swz)
    ushort_t* Atl = pool + 4096;     // [16][256] bf16 (swz)
    ushort_t* Rg  = pool + 8192;     // 64 KB region
    ushort_t* Xt  = Rg;              // [16][256] during Q gemm
    ushort_t* Ytc = Rg;              // [64][CIN] per chunk
    ushort_t* Ztc = Rg + 8192;       // [64][128]
    ushort_t* Kc  = Rg + 16384;      // [64 col][128 hd]
    ushort_t* Vc  = Rg + 24576;      // [128 hd][64 col]
    float*    psh = (float*)Rg;      // [16][20] f32, overlays Ytc

    const ushort_t* qwb  = (const ushort_t*)(ws + WS_QW);
    const ushort_t* pwb  = (const ushort_t*)(ws + WS_PW);
    const ushort_t* kw0b = (const ushort_t*)(ws + WS_KW0);
    const ushort_t* kw1b = (const ushort_t*)(ws + WS_KW1);
    const ushort_t* cw0b = (const ushort_t*)(ws + WS_CW0);
    const ushort_t* cw1b = (const ushort_t*)(ws + WS_CW1);
    const float* cb0 = (const float*)(ws + WS_CB0);
    const float* cb1 = (const float*)(ws + WS_CB1);

    const int tid = threadIdx.x;
    const int w = tid >> 6, lane = tid & 63, l15 = lane & 15, lk = lane >> 4;
    const int b  = blockIdx.x >> 9;
    const int n0 = (blockIdx.x & 511) << 4;

    // ---- S1: x tile -> Xt[n][c] bf16 ----
    {
        const float* xp = x + ((size_t)(b * Cc + tid)) * Nn + n0;
        float xv[16];
        #pragma unroll
        for (int q = 0; q < 4; ++q) {
            const float4 t4 = *(const float4*)(xp + q * 4);
            xv[q * 4] = t4.x; xv[q * 4 + 1] = t4.y; xv[q * 4 + 2] = t4.z; xv[q * 4 + 3] = t4.w;
        }
        #pragma unroll
        for (int p = 0; p < 16; ++p) Xt[swz<256>(p, tid)] = (ushort_t)f2b(xv[p]);
    }
    __syncthreads();

    // ---- S2: Q GEMM: Q[256 o][16 n] = QW[o][c] * X[c][n] ----
    {
        f32x4 acc[4];
        #pragma unroll
        for (int i = 0; i < 4; ++i) acc[i] = f32x4{0.f, 0.f, 0.f, 0.f};
        #pragma unroll
        for (int k = 0; k < 8; ++k) {
            bf16x8 bf = *(const bf16x8*)(Xt + swz<256>(l15, k * 32 + lk * 8));
            #pragma unroll
            for (int i = 0; i < 4; ++i) {
                const int m = w * 4 + i;
                bf16x8 af = *(const bf16x8*)(qwb + (m * 16 + l15) * 256 + k * 32 + lk * 8);
                acc[i] = MFMA(af, bf, acc[i]);
            }
        }
        #pragma unroll
        for (int i = 0; i < 4; ++i) {
            const int ch0 = (w * 4 + i) * 16 + lk * 4;
            const int off = swz<256>(l15, ch0);
            *(uint_t*)(Qs + off)     = f2b(acc[i].x) | (f2b(acc[i].y) << 16);
            *(uint_t*)(Qs + off + 2) = f2b(acc[i].z) | (f2b(acc[i].w) << 16);
        }
    }
    __syncthreads();

    // ---- S3: branches ----
    #pragma unroll 1
    for (int cc = 0; cc < 4; ++cc)
        scale_branch_chunk<64>(tid, b, n0, cc * 4, 0, y0, cw0b, cb0, kw0b,
                               Ytc, Ztc, Kc, Vc, psh, Qs, Atl);
    #pragma unroll 1
    for (int cc = 0; cc < 4; ++cc)
        scale_branch_chunk<128>(tid, b, n0, cc * 4, 128, y1, cw1b, cb1, kw1b,
                                Ytc, Ztc, Kc, Vc, psh, Qs, Atl);

    // ---- S4: proj GEMM + bias -> out ----
    {
        f32x4 acc[4];
        #pragma unroll
        for (int i = 0; i < 4; ++i) acc[i] = f32x4{0.f, 0.f, 0.f, 0.f};
        #pragma unroll
        for (int k = 0; k < 8; ++k) {
            bf16x8 bf = *(const bf16x8*)(Atl + swz<256>(l15, k * 32 + lk * 8));
            #pragma unroll
            for (int i = 0; i < 4; ++i) {
                const int m = w * 4 + i;
                bf16x8 af = *(const bf16x8*)(pwb + (m * 16 + l15) * 256 + k * 32 + lk * 8);
                acc[i] = MFMA(af, bf, acc[i]);
            }
        }
        #pragma unroll
        for (int i = 0; i < 4; ++i) {
            #pragma unroll
            for (int r = 0; r < 4; ++r) {
                const int co = (w * 4 + i) * 16 + lk * 4 + r;
                out[((size_t)(b * Cc + co)) * Nn + n0 + l15] = acc[i][r] + proj_b[co];
            }
        }
    }
}

extern "C" void kernel_launch(void* const* d_in, const int* in_sizes, int n_in,
                              void* d_out, int out_size, void* d_ws, size_t ws_size,
                              hipStream_t stream) {
    const float* x       = (const float*)d_in[0];
    const float* y0      = (const float*)d_in[1];
    const float* y1      = (const float*)d_in[2];
    const float* q_w     = (const float*)d_in[3];
    const float* conv0_w = (const float*)d_in[4];
    const float* bn0_g   = (const float*)d_in[5];
    const float* bn0_b   = (const float*)d_in[6];
    const float* bn0_m   = (const float*)d_in[7];
    const float* bn0_v   = (const float*)d_in[8];
    const float* kv0_w   = (const float*)d_in[9];
    const float* conv1_w = (const float*)d_in[10];
    const float* bn1_g   = (const float*)d_in[11];
    const float* bn1_b   = (const float*)d_in[12];
    const float* bn1_m   = (const float*)d_in[13];
    const float* bn1_v   = (const float*)d_in[14];
    const float* kv1_w   = (const float*)d_in[15];
    const float* proj_w  = (const float*)d_in[16];
    const float* proj_b  = (const float*)d_in[17];

    plsa_prep<<<256, 256, 0, stream>>>(q_w, conv0_w, bn0_g, bn0_b, bn0_m, bn0_v, kv0_w,
                                       conv1_w, bn1_g, bn1_b, bn1_m, bn1_v, kv1_w,
                                       proj_w, (char*)d_ws);

    plsa_mfma<<<Bn * (Nn / 16), 256, 0, stream>>>(
        x, y0, y1, (const char*)d_ws, proj_b, (float*)d_out);
}

// Round 3
// 529.065 us; speedup vs baseline: 7.9796x; 4.0226x over previous
//
#include <hip/hip_runtime.h>

typedef __attribute__((ext_vector_type(8))) short bf16x8;
typedef __attribute__((ext_vector_type(4))) float f32x4;
typedef unsigned short ushort_t;
typedef unsigned int uint_t;

#define MFMA(a, b, c) __builtin_amdgcn_mfma_f32_16x16x32_bf16(a, b, c, 0, 0, 0)

namespace {
constexpr int Bn = 4;
constexpr int Nn = 8192;
constexpr float SCALEf = 0.17677669529663687f; // 32^-0.5
constexpr float EPSf = 1e-5f;

// d_ws byte offsets
constexpr size_t WS_QW  = 0;        // 256*256*2
constexpr size_t WS_PW  = 131072;
constexpr size_t WS_KW0 = 262144;   // 256*128*2
constexpr size_t WS_KW1 = 327680;
constexpr size_t WS_CW0 = 393216;   // 128*64*2
constexpr size_t WS_CW1 = 409600;   // 128*128*2
constexpr size_t WS_CB0 = 442368;   // 128*4 f32
constexpr size_t WS_CB1 = 442880;
constexpr size_t WS_Q   = 458752;               // q  [4][8192][256] bf16 = 16.8MB
constexpr size_t WS_AO  = WS_Q + 16777216;      // ao [4][8192][256] bf16
}

__device__ __forceinline__ uint_t f2b(float f) {
    union { float f; uint_t u; } v; v.f = f;
    return (v.u + 0x7fffu + ((v.u >> 16) & 1u)) >> 16;   // RNE
}
__device__ __forceinline__ float b2f(ushort_t u) {
    union { uint_t u; float f; } v; v.u = ((uint_t)u) << 16;
    return v.f;
}

template<int KC>
__device__ __forceinline__ int swz(int r, int c) {
    constexpr int SW = (KC / 8 < 16 ? KC / 8 : 16);
    return r * KC + ((((c >> 3) ^ (r & (SW - 1))) << 3) | (c & 7));
}

// -------- prep: f32 weights -> bf16 (+ BN fold) --------
__global__ void plsa_prep(const float* __restrict__ qw,
                          const float* __restrict__ c0w, const float* __restrict__ g0,
                          const float* __restrict__ b0,  const float* __restrict__ m0,
                          const float* __restrict__ v0,  const float* __restrict__ k0w,
                          const float* __restrict__ c1w, const float* __restrict__ g1,
                          const float* __restrict__ b1,  const float* __restrict__ m1,
                          const float* __restrict__ v1,  const float* __restrict__ k1w,
                          const float* __restrict__ pw,  char* ws) {
    const int i = blockIdx.x * 256 + threadIdx.x;   // 0 .. 65535
    ((ushort_t*)(ws + WS_QW))[i] = (ushort_t)f2b(qw[i]);
    ((ushort_t*)(ws + WS_PW))[i] = (ushort_t)f2b(pw[i]);
    if (i < 32768) {
        ((ushort_t*)(ws + WS_KW0))[i] = (ushort_t)f2b(k0w[i]);
        ((ushort_t*)(ws + WS_KW1))[i] = (ushort_t)f2b(k1w[i]);
    }
    if (i < 8192)  { int o = i >> 6;  float inv = g0[o] * rsqrtf(v0[o] + EPSf);
                     ((ushort_t*)(ws + WS_CW0))[i] = (ushort_t)f2b(c0w[i] * inv); }
    if (i < 16384) { int o = i >> 7;  float inv = g1[o] * rsqrtf(v1[o] + EPSf);
                     ((ushort_t*)(ws + WS_CW1))[i] = (ushort_t)f2b(c1w[i] * inv); }
    if (i < 128) {
        float i0 = g0[i] * rsqrtf(v0[i] + EPSf);
        float i1 = g1[i] * rsqrtf(v1[i] + EPSf);
        ((float*)(ws + WS_CB0))[i] = b0[i] - m0[i] * i0;
        ((float*)(ws + WS_CB1))[i] = b1[i] - m1[i] * i1;
    }
}

// -------- K1: Q GEMM  q[b][n][ch] bf16 --------
__global__ __launch_bounds__(256, 2) void k_q(const float* __restrict__ x, char* ws) {
    __shared__ __align__(16) ushort_t Xt[64 * 256];
    const ushort_t* qwb = (const ushort_t*)(ws + WS_QW);
    ushort_t* qbuf = (ushort_t*)(ws + WS_Q);
    const int tid = threadIdx.x;
    const int b = blockIdx.x >> 7, n0 = (blockIdx.x & 127) * 64;

    {   // stage x[256 c][64 n] -> Xt[n][c] bf16 (pairs of c)
        const int n = tid & 63, pg = tid >> 6;
        #pragma unroll
        for (int i = 0; i < 32; ++i) {
            const int p = pg + i * 4;       // c-pair 0..127
            const float* xs = x + ((size_t)(b * 256 + 2 * p)) * Nn + n0 + n;
            *(uint_t*)(Xt + swz<256>(n, 2 * p)) = f2b(xs[0]) | (f2b(xs[Nn]) << 16);
        }
    }
    __syncthreads();

    const int w = tid >> 6, lane = tid & 63, l15 = lane & 15, lk = lane >> 4;
    #pragma unroll
    for (int mi = 0; mi < 4; ++mi) {
        bf16x8 af[8];
        #pragma unroll
        for (int k = 0; k < 8; ++k)
            af[k] = *(const bf16x8*)(qwb + (w * 64 + mi * 16 + l15) * 256 + k * 32 + lk * 8);
        #pragma unroll
        for (int ct = 0; ct < 4; ++ct) {
            f32x4 acc = f32x4{0.f, 0.f, 0.f, 0.f};
            #pragma unroll
            for (int k = 0; k < 8; ++k) {
                bf16x8 bf = *(const bf16x8*)(Xt + swz<256>(ct * 16 + l15, k * 32 + lk * 8));
                acc = MFMA(af[k], bf, acc);
            }
            const int nn = n0 + ct * 16 + l15;
            const int ch0 = w * 64 + mi * 16 + lk * 4;
            uint2 u;
            u.x = f2b(acc.x) | (f2b(acc.y) << 16);
            u.y = f2b(acc.z) | (f2b(acc.w) << 16);
            *(uint2*)(qbuf + ((size_t)(b * Nn + nn)) * 256 + ch0) = u;
        }
    }
}

// -------- K2/K3: scale-branch kernel (16 points per block) --------
template<int CIN>
__global__ __launch_bounds__(256, 2) void k_branch(const float* __restrict__ yb, char* ws) {
    constexpr size_t wcw = (CIN == 64) ? WS_CW0 : WS_CW1;
    constexpr size_t wcb = (CIN == 64) ? WS_CB0 : WS_CB1;
    constexpr size_t wkw = (CIN == 64) ? WS_KW0 : WS_KW1;
    constexpr int qb = (CIN == 64) ? 0 : 128;
    constexpr int KT = CIN / 32;

    __shared__ __align__(16) ushort_t qs[2048];    // [16 pt][128 ch]
    __shared__ __align__(16) ushort_t Atl[2048];   // [16 pt][128 ch]
    __shared__ __align__(16) ushort_t Ys[8192];    // [64 col][CIN]
    __shared__ __align__(16) ushort_t Zs[8192];    // [64 col][128 o]
    __shared__ __align__(16) ushort_t Ks[8192];    // [64 col][128 hd]
    __shared__ __align__(16) ushort_t Vs[8192];    // [128 hd][64 col]
    __shared__ float psh[320];                     // [16][20]

    const ushort_t* cwb = (const ushort_t*)(ws + wcw);
    const float*    cbb = (const float*)(ws + wcb);
    const ushort_t* kwb = (const ushort_t*)(ws + wkw);
    const ushort_t* qbuf = (const ushort_t*)(ws + WS_Q);
    ushort_t* aobuf = (ushort_t*)(ws + WS_AO);

    const int tid = threadIdx.x;
    const int w = tid >> 6, lane = tid & 63, l15 = lane & 15, lk = lane >> 4;
    const int b = blockIdx.x >> 9, n0 = (blockIdx.x & 511) << 4;

    // hoist weights into VGPRs (each matrix read once per block)
    bf16x8 cwf[2 * KT];
    float4 cbv[2];
    #pragma unroll
    for (int mi = 0; mi < 2; ++mi) {
        #pragma unroll
        for (int k = 0; k < KT; ++k)
            cwf[mi * KT + k] = *(const bf16x8*)(cwb + ((w * 2 + mi) * 16 + l15) * CIN + k * 32 + lk * 8);
        cbv[mi] = *(const float4*)(cbb + (w * 2 + mi) * 16 + lk * 4);
    }
    bf16x8 kwf[16];
    #pragma unroll
    for (int mi = 0; mi < 4; ++mi)
        #pragma unroll
        for (int k = 0; k < 4; ++k)
            kwf[mi * 4 + k] = *(const bf16x8*)(kwb + ((w * 4 + mi) * 16 + l15) * 128 + k * 32 + lk * 8);

    // stage q tile: 16 pts x 128 ch
    {
        const int pt = tid >> 4, ch0 = (tid & 15) * 8;
        *(uint4*)(qs + pt * 128 + ch0) =
            *(const uint4*)(qbuf + ((size_t)(b * Nn + n0 + pt)) * 256 + qb + ch0);
    }

    #pragma unroll 1
    for (int cc = 0; cc < 4; ++cc) {
        // ---- stage Y (4 pts = 64 cols) ----
        {
            constexpr int ITER = CIN * 64 / 512;
            #pragma unroll
            for (int it = 0; it < ITER; ++it) {
                const int idx = tid + it * 256;
                const int pk = idx & 63, c0 = (idx >> 6) * 2;
                const float* ysrc = yb + ((size_t)(b * CIN + c0)) * (Nn * 16)
                                       + (size_t)(n0 + cc * 4 + (pk >> 4)) * 16 + (pk & 15);
                *(uint_t*)(Ys + swz<CIN>(pk, c0)) = f2b(ysrc[0]) | (f2b(ysrc[Nn * 16]) << 16);
            }
        }
        __syncthreads();

        // ---- conv + BN + ReLU -> Zs[col][o] ----
        #pragma unroll
        for (int ct = 0; ct < 4; ++ct) {
            bf16x8 bf[KT];
            #pragma unroll
            for (int k = 0; k < KT; ++k)
                bf[k] = *(const bf16x8*)(Ys + swz<CIN>(ct * 16 + l15, k * 32 + lk * 8));
            #pragma unroll
            for (int mi = 0; mi < 2; ++mi) {
                f32x4 a = f32x4{0.f, 0.f, 0.f, 0.f};
                #pragma unroll
                for (int k = 0; k < KT; ++k) a = MFMA(cwf[mi * KT + k], bf[k], a);
                const int col = ct * 16 + l15;
                const int o0 = (w * 2 + mi) * 16 + lk * 4;
                const float z0 = fmaxf(a.x + cbv[mi].x, 0.f);
                const float z1 = fmaxf(a.y + cbv[mi].y, 0.f);
                const float z2 = fmaxf(a.z + cbv[mi].z, 0.f);
                const float z3 = fmaxf(a.w + cbv[mi].w, 0.f);
                const int off = swz<128>(col, o0);
                *(uint_t*)(Zs + off)     = f2b(z0) | (f2b(z1) << 16);
                *(uint_t*)(Zs + off + 2) = f2b(z2) | (f2b(z3) << 16);
            }
        }
        __syncthreads();

        // ---- kv GEMM -> split K / V ----
        #pragma unroll
        for (int ct = 0; ct < 4; ++ct) {
            bf16x8 bfr[4];
            #pragma unroll
            for (int k = 0; k < 4; ++k)
                bfr[k] = *(const bf16x8*)(Zs + swz<128>(ct * 16 + l15, k * 32 + lk * 8));
            const int col = ct * 16 + l15;
            #pragma unroll
            for (int mi = 0; mi < 4; ++mi) {
                f32x4 a = f32x4{0.f, 0.f, 0.f, 0.f};
                #pragma unroll
                for (int k = 0; k < 4; ++k) a = MFMA(kwf[mi * 4 + k], bfr[k], a);
                const int j0 = (w * 4 + mi) * 16 + lk * 4;
                const int h = j0 >> 6;
                const int d0 = (j0 & 63) >> 1;   // even
                *(uint_t*)(Ks + swz<128>(col, h * 32 + d0)) = f2b(a.x) | (f2b(a.z) << 16);
                Vs[swz<64>(h * 32 + d0,     col)] = (ushort_t)f2b(a.y);
                Vs[swz<64>(h * 32 + d0 + 1, col)] = (ushort_t)f2b(a.w);
            }
        }
        __syncthreads();

        // ---- logits + softmax : thread = (pt=wave, h=lk, kk=l15) ----
        {
            const int n = tid >> 6, h = lk, kk = l15;
            float s = 0.f;
            #pragma unroll
            for (int dc = 0; dc < 4; ++dc) {
                bf16x8 q8 = *(const bf16x8*)(qs + (cc * 4 + n) * 128 + h * 32 + dc * 8);
                bf16x8 k8 = *(const bf16x8*)(Ks + swz<128>(n * 16 + kk, h * 32 + dc * 8));
                #pragma unroll
                for (int j = 0; j < 8; ++j)
                    s += b2f((ushort_t)q8[j]) * b2f((ushort_t)k8[j]);
            }
            s *= SCALEf;
            float mx = s;
            #pragma unroll
            for (int msk = 1; msk < 16; msk <<= 1) mx = fmaxf(mx, __shfl_xor(mx, msk));
            const float e = __expf(s - mx);
            float sum = e;
            #pragma unroll
            for (int msk = 1; msk < 16; msk <<= 1) sum += __shfl_xor(sum, msk);
            psh[(n * 4 + h) * 20 + kk] = e / sum;
        }
        __syncthreads();

        // ---- PV -> Atl ----
        {
            const int n = tid >> 6, h = lk, dd = l15;
            float pv[16];
            #pragma unroll
            for (int kk = 0; kk < 16; ++kk) pv[kk] = psh[(n * 4 + h) * 20 + kk];
            bf16x8 va = *(const bf16x8*)(Vs + swz<64>(h * 32 + dd, 0) + ((swz<64>(0, (tid>>6)*16) - 0)));
            // (recompute cleanly below)
            const int nb = n * 16;
            va = *(const bf16x8*)(Vs + swz<64>(h * 32 + dd, nb));
            bf16x8 vb = *(const bf16x8*)(Vs + swz<64>(h * 32 + dd, nb + 8));
            bf16x8 vc = *(const bf16x8*)(Vs + swz<64>(h * 32 + dd + 16, nb));
            bf16x8 vd = *(const bf16x8*)(Vs + swz<64>(h * 32 + dd + 16, nb + 8));
            float o_lo = 0.f, o_hi = 0.f;
            #pragma unroll
            for (int j = 0; j < 8; ++j) {
                o_lo += pv[j] * b2f((ushort_t)va[j]);
                o_lo += pv[8 + j] * b2f((ushort_t)vb[j]);
                o_hi += pv[j] * b2f((ushort_t)vc[j]);
                o_hi += pv[8 + j] * b2f((ushort_t)vd[j]);
            }
            Atl[(cc * 4 + n) * 128 + h * 32 + dd]      = (ushort_t)f2b(o_lo);
            Atl[(cc * 4 + n) * 128 + h * 32 + dd + 16] = (ushort_t)f2b(o_hi);
        }
        __syncthreads();
    }

    // ---- store attn-out tile ----
    {
        const int pt = tid >> 4, ch0 = (tid & 15) * 8;
        *(uint4*)(aobuf + ((size_t)(b * Nn + n0 + pt)) * 256 + qb + ch0) =
            *(const uint4*)(Atl + pt * 128 + ch0);
    }
}

// -------- K4: proj GEMM + bias -> out[b][co][n] f32 --------
__global__ __launch_bounds__(256, 2) void k_proj(const char* __restrict__ ws,
                                                 const float* __restrict__ proj_b,
                                                 float* __restrict__ out) {
    __shared__ __align__(16) ushort_t At[64 * 256];
    const ushort_t* pwb = (const ushort_t*)(ws + WS_PW);
    const ushort_t* aobuf = (const ushort_t*)(ws + WS_AO);
    const int tid = threadIdx.x;
    const int b = blockIdx.x >> 7, n0 = (blockIdx.x & 127) * 64;

    {   // stage ao[n][ch] -> At[n][c] (bf16 pairs)
        const int cp = tid & 127, ng = tid >> 7;
        #pragma unroll
        for (int i = 0; i < 32; ++i) {
            const int n = ng + i * 2;
            const uint_t u = *(const uint_t*)(aobuf + ((size_t)(b * Nn + n0 + n)) * 256 + cp * 2);
            *(uint_t*)(At + swz<256>(n, cp * 2)) = u;
        }
    }
    __syncthreads();

    const int w = tid >> 6, lane = tid & 63, l15 = lane & 15, lk = lane >> 4;
    #pragma unroll
    for (int mi = 0; mi < 4; ++mi) {
        bf16x8 af[8];
        #pragma unroll
        for (int k = 0; k < 8; ++k)
            af[k] = *(const bf16x8*)(pwb + (w * 64 + mi * 16 + l15) * 256 + k * 32 + lk * 8);
        const int ch0 = w * 64 + mi * 16 + lk * 4;
        const float4 pbv = *(const float4*)(proj_b + ch0);
        #pragma unroll
        for (int ct = 0; ct < 4; ++ct) {
            f32x4 acc = f32x4{0.f, 0.f, 0.f, 0.f};
            #pragma unroll
            for (int k = 0; k < 8; ++k) {
                bf16x8 bf = *(const bf16x8*)(At + swz<256>(ct * 16 + l15, k * 32 + lk * 8));
                acc = MFMA(af[k], bf, acc);
            }
            const int nn = n0 + ct * 16 + l15;
            out[((size_t)(b * 256 + ch0 + 0)) * Nn + nn] = acc.x + pbv.x;
            out[((size_t)(b * 256 + ch0 + 1)) * Nn + nn] = acc.y + pbv.y;
            out[((size_t)(b * 256 + ch0 + 2)) * Nn + nn] = acc.z + pbv.z;
            out[((size_t)(b * 256 + ch0 + 3)) * Nn + nn] = acc.w + pbv.w;
        }
    }
}

extern "C" void kernel_launch(void* const* d_in, const int* in_sizes, int n_in,
                              void* d_out, int out_size, void* d_ws, size_t ws_size,
                              hipStream_t stream) {
    const float* x       = (const float*)d_in[0];
    const float* y0      = (const float*)d_in[1];
    const float* y1      = (const float*)d_in[2];
    const float* q_w     = (const float*)d_in[3];
    const float* conv0_w = (const float*)d_in[4];
    const float* bn0_g   = (const float*)d_in[5];
    const float* bn0_b   = (const float*)d_in[6];
    const float* bn0_m   = (const float*)d_in[7];
    const float* bn0_v   = (const float*)d_in[8];
    const float* kv0_w   = (const float*)d_in[9];
    const float* conv1_w = (const float*)d_in[10];
    const float* bn1_g   = (const float*)d_in[11];
    const float* bn1_b   = (const float*)d_in[12];
    const float* bn1_m   = (const float*)d_in[13];
    const float* bn1_v   = (const float*)d_in[14];
    const float* kv1_w   = (const float*)d_in[15];
    const float* proj_w  = (const float*)d_in[16];
    const float* proj_b  = (const float*)d_in[17];
    char* ws = (char*)d_ws;

    plsa_prep<<<256, 256, 0, stream>>>(q_w, conv0_w, bn0_g, bn0_b, bn0_m, bn0_v, kv0_w,
                                       conv1_w, bn1_g, bn1_b, bn1_m, bn1_v, kv1_w,
                                       proj_w, ws);
    k_q<<<Bn * (Nn / 64), 256, 0, stream>>>(x, ws);
    k_branch<64><<<Bn * (Nn / 16), 256, 0, stream>>>(y0, ws);
    k_branch<128><<<Bn * (Nn / 16), 256, 0, stream>>>(y1, ws);
    k_proj<<<Bn * (Nn / 64), 256, 0, stream>>>(ws, proj_b, (float*)d_out);
}